// Round 20
// baseline (171.554 us; speedup 1.0000x reference)
//
#include <hip/hip_runtime.h>

typedef unsigned short u16;
typedef unsigned int u32;
typedef u16 u16x8 __attribute__((ext_vector_type(8)));
typedef u16 u16x4 __attribute__((ext_vector_type(4)));
typedef __bf16 bf16x8 __attribute__((ext_vector_type(8)));
typedef float f32x4 __attribute__((ext_vector_type(4)));

// ---------- helpers ----------
__device__ __forceinline__ u16 f2bf(float f) {
    u32 u = __builtin_bit_cast(u32, f);
    u32 r = (u + 0x7fffu + ((u >> 16) & 1u)) >> 16;
    return (u16)r;
}
__device__ __forceinline__ void async16(const u16* g, u16* lds_base) {
    __builtin_amdgcn_global_load_lds(
        (const __attribute__((address_space(1))) void*)g,
        (__attribute__((address_space(3))) void*)lds_base, 16, 0, 0);
}
template <bool SW>
__device__ __forceinline__ f32x4 mf(bf16x8 a, bf16x8 b, f32x4 c) {
    if constexpr (SW) return __builtin_amdgcn_mfma_f32_16x16x32_bf16(b, a, c, 0, 0, 0);
    else              return __builtin_amdgcn_mfma_f32_16x16x32_bf16(a, b, c, 0, 0, 0);
}

#define BAR __builtin_amdgcn_s_barrier()
#define WAITLGK do { asm volatile("s_waitcnt lgkmcnt(0)" ::: "memory"); \
                     __builtin_amdgcn_sched_barrier(0); } while (0)
#define PRIO1 __builtin_amdgcn_s_setprio(1)
#define PRIO0 __builtin_amdgcn_s_setprio(0)
#define VM(n) asm volatile("s_waitcnt vmcnt(" #n ")" ::: "memory")

// ========== prep: one launch for x->xb/xbT, Wq/Wo cvt, Wk/Wv transpose-cvt ==========
__global__ __launch_bounds__(256) void prep(
    const float* __restrict__ x, u16* __restrict__ xb, u16* __restrict__ xbT,
    const float* __restrict__ wq, u16* __restrict__ wqb,
    const float* __restrict__ wo, u16* __restrict__ wob,
    const float* __restrict__ wk, const float* __restrict__ wv,
    u16* __restrict__ WkvT) {
    const int bid = blockIdx.x;
    const int t = threadIdx.x;
    if (bid < 16384) {
        __shared__ u16 tile[32][33];
        const int s0 = (bid >> 5) * 32, n0 = (bid & 31) * 32;
        const int tx = t & 31, ty = t >> 5;
#pragma unroll
        for (int r = 0; r < 4; ++r) {
            const int s = s0 + ty + 8 * r;
            const u16 bv = f2bf(x[(size_t)s * 1024 + n0 + tx]);
            xb[(size_t)s * 1024 + n0 + tx] = bv;
            tile[ty + 8 * r][tx] = bv;
        }
        __syncthreads();
        const int b = s0 >> 12;
        const int sl = s0 & 4095;
#pragma unroll
        for (int r = 0; r < 4; ++r) {
            const int n = n0 + ty + 8 * r;
            xbT[((size_t)b * 1024 + n) * 4096 + sl + tx] = tile[tx][ty + 8 * r];
        }
    } else if (bid < 17408) {
        const int b2 = bid - 16384;
        const float* src = b2 < 512 ? wq : wo;
        u16* dst = b2 < 512 ? wqb : wob;
        const long base = b2 < 512 ? b2 : b2 - 512;
        const long idx = (base * 256 + t) * 8;
        float4 a = *(const float4*)(src + idx);
        float4 b = *(const float4*)(src + idx + 4);
        u16x8 o;
        o[0] = f2bf(a.x); o[1] = f2bf(a.y); o[2] = f2bf(a.z); o[3] = f2bf(a.w);
        o[4] = f2bf(b.x); o[5] = f2bf(b.y); o[6] = f2bf(b.z); o[7] = f2bf(b.w);
        *(u16x8*)(dst + idx) = o;
    } else {
        __shared__ float tf[32][33];
        const int b3 = bid - 17408;
        const float* W = (b3 >> 10) == 0 ? wk : wv;
        const int n0 = (b3 & 31) * 32, k0 = ((b3 >> 5) & 31) * 32;
        const int tx = t & 31, ty = t >> 5;
#pragma unroll
        for (int r = 0; r < 4; ++r)
            tf[ty + 8 * r][tx] = W[(size_t)(k0 + ty + 8 * r) * 1024 + n0 + tx];
        __syncthreads();
#pragma unroll
        for (int r = 0; r < 4; ++r) {
            const int n = n0 + ty + 8 * r;
            WkvT[((size_t)(b3 >> 10) * 1024 + n) * 1024 + k0 + tx] =
                f2bf(tf[tx][ty + 8 * r]);
        }
    }
}

// ---------- storeC helpers for gemmS ----------
__device__ __forceinline__ void stc4(u16* p, f32x4 v) {
    u16x4 o; o[0] = f2bf(v[0]); o[1] = f2bf(v[1]); o[2] = f2bf(v[2]); o[3] = f2bf(v[3]);
    *(u16x4*)p = o;
}
__device__ __forceinline__ void stc4(float* p, f32x4 v) { *(f32x4*)p = v; }

// ========== gemmS: 128x128 tile, 512 thr (8 waves), 4-buffer depth-3 prefetch ==========
// C[m][n] = sum_{k in [kOff,kOff+K)} A[(m&aMask)+..][k] * Bt[n][k].
// kSplit>1: grid = kSplit*nMT*nTN; id -> (half, tile); A/Bt advanced by half*K.
template <typename OutT>
__global__ __launch_bounds__(512, 1) void gemmS(
    const u16* __restrict__ A, int lda,
    const u16* __restrict__ Bt, int ldb,
    OutT* __restrict__ C, int ldc, int K, int nTN,
    size_t aMask, size_t btStrideB, int kSplit, size_t cStrideH) {
    __shared__ u16 SM[4][2][128 * 64];
    const int tid = threadIdx.x, wid = tid >> 6, lane = tid & 63;
    const int wm = wid >> 2, wn = wid & 3;

    const int nwg = gridDim.x;
    const int orig = blockIdx.x;
    int id = (orig & 7) * (nwg >> 3) + (orig >> 3);
    const int perH = nwg / kSplit;
    const int half = id / perH;
    id -= half * perH;
    const size_t mBase = (size_t)(id / nTN) * 128;
    const size_t nBase = (size_t)(id % nTN) * 128;
    const size_t mA = mBase & aMask;
    const size_t kOff = (size_t)half * K;
    A += kOff;
    Bt += (mBase >> 10) * btStrideB + kOff;
    C += (size_t)half * cStrideH;

    const int srow = lane >> 3;
    const int scol = ((lane & 7) ^ (srow & 7)) * 8;

    auto stageS = [&](int buf, int kt) {
#pragma unroll
        for (int c = 0; c < 2; ++c) {
            const u16* g = c ? Bt : A;
            const int ld = c ? ldb : lda;
            const size_t rb = c ? nBase : mA;
            u16* lds = SM[buf][c];
#pragma unroll
            for (int j = 0; j < 2; ++j) {
                const int rowL = wid * 16 + j * 8;
                async16(g + (rb + rowL + srow) * (size_t)ld + (size_t)kt * 64 + scol,
                        lds + rowL * 64);
            }
        }
    };

    const int frow = lane & 15;
    const int xs0 = ((lane >> 4) ^ (frow & 7)) * 8;
    const int xs1 = ((4 + (lane >> 4)) ^ (frow & 7)) * 8;
    f32x4 acc[4][2] = {};

    const int nk = K >> 6;
    stageS(0, 0); stageS(1, 1); stageS(2, 2);
    VM(8);
    BAR;

    for (int kt = 0; kt < nk; ++kt) {
        const int cur = kt & 3;
        if (kt + 3 < nk) stageS((kt + 3) & 3, kt + 3);
        bf16x8 aF[4][2], bF[2][2];
#pragma unroll
        for (int mi = 0; mi < 4; ++mi) {
            const int rA = (wm * 64 + mi * 16 + frow) * 64;
            aF[mi][0] = *(const bf16x8*)&SM[cur][0][rA + xs0];
            aF[mi][1] = *(const bf16x8*)&SM[cur][0][rA + xs1];
        }
#pragma unroll
        for (int ni = 0; ni < 2; ++ni) {
            const int rB = (wn * 32 + ni * 16 + frow) * 64;
            bF[ni][0] = *(const bf16x8*)&SM[cur][1][rB + xs0];
            bF[ni][1] = *(const bf16x8*)&SM[cur][1][rB + xs1];
        }
        WAITLGK;
        PRIO1;
#pragma unroll
        for (int mi = 0; mi < 4; ++mi)
#pragma unroll
            for (int ni = 0; ni < 2; ++ni)
#pragma unroll
                for (int s = 0; s < 2; ++s)
                    acc[mi][ni] = mf<true>(aF[mi][s], bF[ni][s], acc[mi][ni]);
        PRIO0;
        if (kt + 3 < nk)      { VM(8); }
        else if (kt + 2 < nk) { VM(4); }
        else if (kt + 1 < nk) { VM(0); }
        BAR;
    }

    const int rb4 = (lane >> 4) * 4, cx = lane & 15;
#pragma unroll
    for (int mi = 0; mi < 4; ++mi) {
        const size_t row = mBase + wm * 64 + mi * 16 + cx;
#pragma unroll
        for (int ni = 0; ni < 2; ++ni) {
            const size_t col = nBase + wn * 32 + ni * 16 + rb4;
            stc4(&C[row * (size_t)ldc + col], acc[mi][ni]);
        }
    }
}

// ---------- add two fp32 partials -> bf16 G ----------
__global__ __launch_bounds__(256) void addcvt(
    const float* __restrict__ P0, const float* __restrict__ P1,
    u16* __restrict__ G) {
    const long i = ((long)blockIdx.x * 256 + threadIdx.x) * 4;
    f32x4 a = *(const f32x4*)(P0 + i);
    f32x4 b = *(const f32x4*)(P1 + i);
    f32x4 s = a + b;
    u16x4 o;
    o[0] = f2bf(s[0]); o[1] = f2bf(s[1]); o[2] = f2bf(s[2]); o[3] = f2bf(s[3]);
    *(u16x4*)(G + i) = o;
}

// ================= 256x256 pipelined bf16 MFMA GEMM (final projection) ========
#define As SM[0]
#define Bs SM[1]

#define LDA(buf, mh) do { _Pragma("unroll") for (int mi = 0; mi < 4; ++mi) { \
    const int rA = (wm * 128 + (mh) * 64 + mi * 16 + frow) * 64; \
    aF[mi][0] = *(const bf16x8*)&As[buf][rA + xs0]; \
    aF[mi][1] = *(const bf16x8*)&As[buf][rA + xs1]; } } while (0)

#define LDB(buf, nh) do { _Pragma("unroll") for (int ni = 0; ni < 2; ++ni) { \
    const int rB = (wn * 64 + (nh) * 32 + ni * 16 + frow) * 64; \
    bF[(nh) * 2 + ni][0] = *(const bf16x8*)&Bs[buf][rB + xs0]; \
    bF[(nh) * 2 + ni][1] = *(const bf16x8*)&Bs[buf][rB + xs1]; } } while (0)

#define MFQ(mh, nh) do { _Pragma("unroll") for (int mi = 0; mi < 4; ++mi) \
  _Pragma("unroll") for (int ni = 0; ni < 2; ++ni) \
  _Pragma("unroll") for (int s = 0; s < 2; ++s) \
    acc[(mh) * 4 + mi][(nh) * 2 + ni] = mf<true>( \
        aF[mi][s], bF[(nh) * 2 + ni][s], acc[(mh) * 4 + mi][(nh) * 2 + ni]); } while (0)

#define TILE4(buf, S2, S3, S4, W1, W2, WV) \
  LDA(buf, 0); LDB(buf, 0); BAR; WAITLGK; PRIO1; MFQ(0, 0); PRIO0; W1; BAR; \
  LDB(buf, 1); S2; BAR; WAITLGK; PRIO1; MFQ(0, 1); PRIO0; W2; BAR; \
  LDA(buf, 1); S3; BAR; WAITLGK; PRIO1; MFQ(1, 1); PRIO0; BAR; \
  S4; BAR; WAITLGK; PRIO1; MFQ(1, 0); PRIO0; WV; BAR;

// out = A @ Bt^T, per-batch Bt (batch = mBase>>12), swapped MFMA, float4 stores.
__global__ __launch_bounds__(512, 2) void gemm8p(
    const u16* __restrict__ A, int lda,
    const u16* __restrict__ Bt, int ldb,
    float* __restrict__ Cq, int ldc, int K, int nTN,
    size_t btStrideB) {
    __shared__ u16 SM[2][2][256 * 64];
    const int tid = threadIdx.x;
    const int wid = tid >> 6, lane = tid & 63;
    const int wm = wid >> 2, wn = wid & 3;

    const int nwg = gridDim.x;
    const int orig = blockIdx.x;
    const int id = (orig & 7) * (nwg >> 3) + (orig >> 3);
    const size_t mBase = (size_t)(id / nTN) * 256;
    const size_t nBase = (size_t)(id % nTN) * 256;

    Bt += (mBase >> 12) * btStrideB;

    const int srow = lane >> 3;
    const int scol = (((lane & 7) ^ (srow & 7)) * 8);

    auto stageH = [&](int buf, int isB, int h, int kt) {
        const u16* g = isB ? Bt : A;
        const int ld = isB ? ldb : lda;
        const size_t rb = isB ? nBase : mBase;
        u16* lds = isB ? Bs[buf] : As[buf];
#pragma unroll
        for (int j = 0; j < 2; ++j) {
            const int rowL = isB ? ((wid >> 1) * 64 + h * 32 + (wid & 1) * 16 + j * 8)
                                 : ((wid >> 2) * 128 + h * 64 + (wid & 3) * 16 + j * 8);
            async16(g + (rb + rowL + srow) * (size_t)ld + (size_t)kt * 64 + scol,
                    lds + rowL * 64);
        }
    };

    const int frow = lane & 15;
    const int xs0 = (((lane >> 4)) ^ (frow & 7)) * 8;
    const int xs1 = ((4 + (lane >> 4)) ^ (frow & 7)) * 8;

    f32x4 acc[8][4] = {};
    bf16x8 aF[4][2], bF[4][2];

#pragma unroll
    for (int h = 0; h < 2; ++h) { stageH(0, 0, h, 0); stageH(0, 1, h, 0); }
#pragma unroll
    for (int h = 0; h < 2; ++h) { stageH(1, 0, h, 1); stageH(1, 1, h, 1); }
    VM(8);
    BAR;

    const int np = K >> 7;
    for (int p = 0; p < np - 1; ++p) {
        const int k2 = 2 * p + 2, k3 = 2 * p + 3;
        TILE4(0,
              { stageH(0, 0, 0, k2); stageH(0, 1, 0, k2); },
              stageH(0, 1, 1, k2),
              stageH(0, 0, 1, k2),
              VM(10), VM(12), VM(12));
        TILE4(1,
              { stageH(1, 0, 0, k3); stageH(1, 1, 0, k3); },
              stageH(1, 1, 1, k3),
              stageH(1, 0, 1, k3),
              VM(10), VM(12), VM(12));
    }
    TILE4(0, , , , , , VM(0));
    TILE4(1, , , , , , );

    const int rb4 = (lane >> 4) * 4;
    const int cx = lane & 15;
#pragma unroll
    for (int m = 0; m < 8; ++m) {
        const size_t row = mBase + wm * 128 + m * 16 + cx;
#pragma unroll
        for (int n = 0; n < 4; ++n) {
            const size_t col = nBase + wn * 64 + n * 16 + rb4;
            *(float4*)&Cq[row * (size_t)ldc + col] = *(float4*)&acc[m][n];
        }
    }
}

// ========== kvw2: fused kv (per b,h) + W2 panels; kv kept in LDS ==========
__global__ __launch_bounds__(256, 2) void kvw2(
    const u16* __restrict__ M1v, const u16* __restrict__ WvT,
    const u16* __restrict__ Wob, u16* __restrict__ W2t) {
    __shared__ u16 Ks[64 * 64];
    __shared__ u16 Vs[64 * 64];
    __shared__ u16 kvs[64 * 64];
    __shared__ u16 Aw[256 * 64];
    const int h = blockIdx.x, b = blockIdx.y;
    const int tid = threadIdx.x, w = tid >> 6, lane = tid & 63;
    const int srow = lane >> 3;
    const int scol = ((lane & 7) ^ srow) * 8;
    const int frow = lane & 15;
    const int xs0 = ((lane >> 4) ^ (frow & 7)) * 8;
    const int xs1 = ((4 + (lane >> 4)) ^ (frow & 7)) * 8;
    const u16* Ap = M1v + (size_t)b * 1048576 + (size_t)h * 64 * 1024;
    const u16* Bp = WvT + (size_t)h * 64 * 1024;
    f32x4 acc[4] = {};
    for (int kk = 0; kk < 16; ++kk) {
        __syncthreads();
#pragma unroll
        for (int j = 0; j < 2; ++j) {
            const int row = w * 16 + j * 8;
            async16(Ap + (size_t)(row + srow) * 1024 + kk * 64 + scol, &Ks[row * 64]);
            async16(Bp + (size_t)(row + srow) * 1024 + kk * 64 + scol, &Vs[row * 64]);
        }
        VM(0);
        __syncthreads();
        bf16x8 a0 = *(const bf16x8*)&Ks[(w * 16 + frow) * 64 + xs0];
        bf16x8 a1 = *(const bf16x8*)&Ks[(w * 16 + frow) * 64 + xs1];
#pragma unroll
        for (int n = 0; n < 4; ++n) {
            bf16x8 b0 = *(const bf16x8*)&Vs[(n * 16 + frow) * 64 + xs0];
            bf16x8 b1 = *(const bf16x8*)&Vs[(n * 16 + frow) * 64 + xs1];
            acc[n] = mf<false>(a0, b0, acc[n]);
            acc[n] = mf<false>(a1, b1, acc[n]);
        }
    }
    {
        const int rb4 = (lane >> 4) * 4, cx = lane & 15;
#pragma unroll
        for (int n = 0; n < 4; ++n) {
            const int col = n * 16 + cx;
            const int unit = col >> 3;
#pragma unroll
            for (int r = 0; r < 4; ++r) {
                const int row = w * 16 + rb4 + r;
                const int byteoff = row * 128 + (((unit ^ (row & 7)) << 4) | ((col & 7) << 1));
                *(u16*)((char*)kvs + byteoff) = f2bf(acc[n][r] * 0.125f);
            }
        }
    }
    __syncthreads();
    u16* outB = W2t + (size_t)b * 1048576;
    for (int eT = 0; eT < 4; ++eT) {
#pragma unroll
        for (int j = 0; j < 8; ++j) {
            const int row = w * 64 + j * 8;
            async16(Wob + (size_t)(eT * 256 + row + srow) * 1024 + h * 64 + scol,
                    &Aw[row * 64]);
        }
        VM(0);
        __syncthreads();
        f32x4 a2[4][4] = {};
#pragma unroll
        for (int m = 0; m < 4; ++m) {
            bf16x8 a0 = *(const bf16x8*)&Aw[(w * 64 + m * 16 + frow) * 64 + xs0];
            bf16x8 a1 = *(const bf16x8*)&Aw[(w * 64 + m * 16 + frow) * 64 + xs1];
#pragma unroll
            for (int n = 0; n < 4; ++n) {
                bf16x8 b0 = *(const bf16x8*)&kvs[(n * 16 + frow) * 64 + xs0];
                bf16x8 b1 = *(const bf16x8*)&kvs[(n * 16 + frow) * 64 + xs1];
                a2[m][n] = mf<false>(a0, b0, a2[m][n]);
                a2[m][n] = mf<false>(a1, b1, a2[m][n]);
            }
        }
        const int rb4 = (lane >> 4) * 4, cx = lane & 15;
#pragma unroll
        for (int m = 0; m < 4; ++m)
#pragma unroll
            for (int n = 0; n < 4; ++n)
#pragma unroll
                for (int r = 0; r < 4; ++r)
                    outB[(size_t)(eT * 256 + w * 64 + m * 16 + rb4 + r) * 1024 +
                         h * 64 + n * 16 + cx] = f2bf(a2[m][n][r]);
        __syncthreads();
    }
}

extern "C" void kernel_launch(void* const* d_in, const int* in_sizes, int n_in,
                              void* d_out, int out_size, void* d_ws, size_t ws_size,
                              hipStream_t stream) {
    const float* x  = (const float*)d_in[0];
    const float* Wq = (const float*)d_in[1];
    const float* Wk = (const float*)d_in[2];
    const float* Wv = (const float*)d_in[3];
    const float* Wo = (const float*)d_in[4];
    float* out = (float*)d_out;
    char* ws = (char*)d_ws;

    u16*   xb   = (u16*)(ws);                  // [16384][1024]        32 MB
    u16*   xbT  = (u16*)(ws + 33554432);       // [4][1024][4096]      32 MB
    u16*   G    = (u16*)(ws + 67108864);       // [4][1024][1024]       8 MB
    u16*   M1v  = (u16*)(ws + 75497472);       // [4][1024][1024]       8 MB
    u16*   WkvT = (u16*)(ws + 83886080);       // [2048][1024]          4 MB
    u16*   Wqb  = (u16*)(ws + 88080384);       // [1024][1024]          2 MB
    u16*   Wob  = (u16*)(ws + 90177536);       // [1024][1024]          2 MB
    u16*   W2t  = (u16*)(ws + 92798976);       // [4][1024][1024]       8 MB
    u16*   W3T  = (u16*)(ws + 101187584);      // [4][1024][1024]       8 MB
    float* Gp   = (float*)(ws + 109576192);    // [2][4][1024][1024]   32 MB
    u16*   WkT  = WkvT;
    u16*   WvT  = WkvT + 1048576;

    prep<<<19456, 256, 0, stream>>>(x, xb, xbT, Wq, Wqb, Wo, Wob, Wk, Wv, WkvT);

    // G_b = x_b^T x_b, K-split 2: 512 blocks, each K=2048 -> fp32 partials
    gemmS<float><<<512, 512, 0, stream>>>(xbT, 4096, xbT, 4096, Gp, 1024, 2048, 8,
                                          ~0ULL, 4194304ULL, 2, 4194304ULL);
    addcvt<<<4096, 256, 0, stream>>>(Gp, Gp + 4194304, G);

    // M1_b = Wk^T G_b (G bitwise symmetric -> G rows serve as Bt)
    gemmS<u16><<<256, 512, 0, stream>>>(WkT, 1024, G, 1024, M1v, 1024, 1024, 8,
                                        1023ULL, 1048576ULL, 1, 0);
    // fused kv + W2 panels
    kvw2<<<dim3(16, 4), 256, 0, stream>>>(M1v, WvT, Wob, W2t);
    // W3T[b*1024+e][d] = sum_k W2t[b][e][k] * Wq[d][k]
    gemmS<u16><<<256, 512, 0, stream>>>(W2t, 1024, Wqb, 1024, W3T, 1024, 1024, 8,
                                        ~0ULL, 0ULL, 1, 0);
    // out = xb @ W3T^T (per-batch Bt); grid 256 (%8==0)
    gemm8p<<<256, 512, 0, stream>>>(xb, 1024, W3T, 1024, out, 1024, 1024, 4, 1048576ULL);
}

// Round 21
// 155.557 us; speedup vs baseline: 1.1028x; 1.1028x over previous
//
#include <hip/hip_runtime.h>

typedef unsigned short u16;
typedef unsigned int u32;
typedef u16 u16x8 __attribute__((ext_vector_type(8)));
typedef u16 u16x4 __attribute__((ext_vector_type(4)));
typedef __bf16 bf16x8 __attribute__((ext_vector_type(8)));
typedef float f32x4 __attribute__((ext_vector_type(4)));

// ---------- helpers ----------
__device__ __forceinline__ u16 f2bf(float f) {
    u32 u = __builtin_bit_cast(u32, f);
    u32 r = (u + 0x7fffu + ((u >> 16) & 1u)) >> 16;
    return (u16)r;
}
__device__ __forceinline__ void async16(const u16* g, u16* lds_base) {
    __builtin_amdgcn_global_load_lds(
        (const __attribute__((address_space(1))) void*)g,
        (__attribute__((address_space(3))) void*)lds_base, 16, 0, 0);
}
template <bool SW>
__device__ __forceinline__ f32x4 mf(bf16x8 a, bf16x8 b, f32x4 c) {
    if constexpr (SW) return __builtin_amdgcn_mfma_f32_16x16x32_bf16(b, a, c, 0, 0, 0);
    else              return __builtin_amdgcn_mfma_f32_16x16x32_bf16(a, b, c, 0, 0, 0);
}

#define BAR __builtin_amdgcn_s_barrier()
#define WAITLGK do { asm volatile("s_waitcnt lgkmcnt(0)" ::: "memory"); \
                     __builtin_amdgcn_sched_barrier(0); } while (0)
#define PRIO1 __builtin_amdgcn_s_setprio(1)
#define PRIO0 __builtin_amdgcn_s_setprio(0)
#define VM(n) asm volatile("s_waitcnt vmcnt(" #n ")" ::: "memory")

// ========== prep: one launch for x->xb/xbT, Wq/Wo cvt, Wk/Wv transpose-cvt ==========
__global__ __launch_bounds__(256) void prep(
    const float* __restrict__ x, u16* __restrict__ xb, u16* __restrict__ xbT,
    const float* __restrict__ wq, u16* __restrict__ wqb,
    const float* __restrict__ wo, u16* __restrict__ wob,
    const float* __restrict__ wk, const float* __restrict__ wv,
    u16* __restrict__ WkvT) {
    const int bid = blockIdx.x;
    const int t = threadIdx.x;
    if (bid < 16384) {
        __shared__ u16 tile[32][33];
        const int s0 = (bid >> 5) * 32, n0 = (bid & 31) * 32;
        const int tx = t & 31, ty = t >> 5;
#pragma unroll
        for (int r = 0; r < 4; ++r) {
            const int s = s0 + ty + 8 * r;
            const u16 bv = f2bf(x[(size_t)s * 1024 + n0 + tx]);
            xb[(size_t)s * 1024 + n0 + tx] = bv;
            tile[ty + 8 * r][tx] = bv;
        }
        __syncthreads();
        const int b = s0 >> 12;
        const int sl = s0 & 4095;
#pragma unroll
        for (int r = 0; r < 4; ++r) {
            const int n = n0 + ty + 8 * r;
            xbT[((size_t)b * 1024 + n) * 4096 + sl + tx] = tile[tx][ty + 8 * r];
        }
    } else if (bid < 17408) {
        const int b2 = bid - 16384;
        const float* src = b2 < 512 ? wq : wo;
        u16* dst = b2 < 512 ? wqb : wob;
        const long base = b2 < 512 ? b2 : b2 - 512;
        const long idx = (base * 256 + t) * 8;
        float4 a = *(const float4*)(src + idx);
        float4 b = *(const float4*)(src + idx + 4);
        u16x8 o;
        o[0] = f2bf(a.x); o[1] = f2bf(a.y); o[2] = f2bf(a.z); o[3] = f2bf(a.w);
        o[4] = f2bf(b.x); o[5] = f2bf(b.y); o[6] = f2bf(b.z); o[7] = f2bf(b.w);
        *(u16x8*)(dst + idx) = o;
    } else {
        __shared__ float tf[32][33];
        const int b3 = bid - 17408;
        const float* W = (b3 >> 10) == 0 ? wk : wv;
        const int n0 = (b3 & 31) * 32, k0 = ((b3 >> 5) & 31) * 32;
        const int tx = t & 31, ty = t >> 5;
#pragma unroll
        for (int r = 0; r < 4; ++r)
            tf[ty + 8 * r][tx] = W[(size_t)(k0 + ty + 8 * r) * 1024 + n0 + tx];
        __syncthreads();
#pragma unroll
        for (int r = 0; r < 4; ++r) {
            const int n = n0 + ty + 8 * r;
            WkvT[((size_t)(b3 >> 10) * 1024 + n) * 1024 + k0 + tx] =
                f2bf(tf[tx][ty + 8 * r]);
        }
    }
}

// ========== gemmS: 128x128 tile, 512 thr (8 waves), 4-buffer depth-3 prefetch ==========
// C[m][n] = sum_k A[(m&aMask)+..][k] * Bt[n][k]; Bt += (mBase>>10)*btStrideB.
__global__ __launch_bounds__(512, 1) void gemmS(
    const u16* __restrict__ A, int lda,
    const u16* __restrict__ Bt, int ldb,
    u16* __restrict__ C, int ldc, int K, int nTN,
    size_t aMask, size_t btStrideB) {
    __shared__ u16 SM[4][2][128 * 64];
    const int tid = threadIdx.x, wid = tid >> 6, lane = tid & 63;
    const int wm = wid >> 2, wn = wid & 3;

    const int nwg = gridDim.x;
    const int orig = blockIdx.x;
    const int id = (orig & 7) * (nwg >> 3) + (orig >> 3);
    const size_t mBase = (size_t)(id / nTN) * 128;
    const size_t nBase = (size_t)(id % nTN) * 128;
    const size_t mA = mBase & aMask;
    Bt += (mBase >> 10) * btStrideB;

    const int srow = lane >> 3;
    const int scol = ((lane & 7) ^ (srow & 7)) * 8;

    auto stageS = [&](int buf, int kt) {
#pragma unroll
        for (int c = 0; c < 2; ++c) {
            const u16* g = c ? Bt : A;
            const int ld = c ? ldb : lda;
            const size_t rb = c ? nBase : mA;
            u16* lds = SM[buf][c];
#pragma unroll
            for (int j = 0; j < 2; ++j) {
                const int rowL = wid * 16 + j * 8;
                async16(g + (rb + rowL + srow) * (size_t)ld + (size_t)kt * 64 + scol,
                        lds + rowL * 64);
            }
        }
    };

    const int frow = lane & 15;
    const int xs0 = ((lane >> 4) ^ (frow & 7)) * 8;
    const int xs1 = ((4 + (lane >> 4)) ^ (frow & 7)) * 8;
    f32x4 acc[4][2] = {};

    const int nk = K >> 6;
    stageS(0, 0); stageS(1, 1); stageS(2, 2);
    VM(8);
    BAR;

    for (int kt = 0; kt < nk; ++kt) {
        const int cur = kt & 3;
        if (kt + 3 < nk) stageS((kt + 3) & 3, kt + 3);
        bf16x8 aF[4][2], bF[2][2];
#pragma unroll
        for (int mi = 0; mi < 4; ++mi) {
            const int rA = (wm * 64 + mi * 16 + frow) * 64;
            aF[mi][0] = *(const bf16x8*)&SM[cur][0][rA + xs0];
            aF[mi][1] = *(const bf16x8*)&SM[cur][0][rA + xs1];
        }
#pragma unroll
        for (int ni = 0; ni < 2; ++ni) {
            const int rB = (wn * 32 + ni * 16 + frow) * 64;
            bF[ni][0] = *(const bf16x8*)&SM[cur][1][rB + xs0];
            bF[ni][1] = *(const bf16x8*)&SM[cur][1][rB + xs1];
        }
        WAITLGK;
        PRIO1;
#pragma unroll
        for (int mi = 0; mi < 4; ++mi)
#pragma unroll
            for (int ni = 0; ni < 2; ++ni)
#pragma unroll
                for (int s = 0; s < 2; ++s)
                    acc[mi][ni] = mf<true>(aF[mi][s], bF[ni][s], acc[mi][ni]);
        PRIO0;
        if (kt + 3 < nk)      { VM(8); }
        else if (kt + 2 < nk) { VM(4); }
        else if (kt + 1 < nk) { VM(0); }
        BAR;
    }

    const int rb4 = (lane >> 4) * 4, cx = lane & 15;
#pragma unroll
    for (int mi = 0; mi < 4; ++mi) {
        const size_t row = mBase + wm * 64 + mi * 16 + cx;
#pragma unroll
        for (int ni = 0; ni < 2; ++ni) {
            const size_t col = nBase + wn * 32 + ni * 16 + rb4;
            u16x4 v;
            v[0] = f2bf(acc[mi][ni][0]); v[1] = f2bf(acc[mi][ni][1]);
            v[2] = f2bf(acc[mi][ni][2]); v[3] = f2bf(acc[mi][ni][3]);
            *(u16x4*)&C[row * (size_t)ldc + col] = v;
        }
    }
}

// ================= 256x256 pipelined bf16 MFMA GEMM (final projection) ========
#define As SM[0]
#define Bs SM[1]

#define LDA(buf, mh) do { _Pragma("unroll") for (int mi = 0; mi < 4; ++mi) { \
    const int rA = (wm * 128 + (mh) * 64 + mi * 16 + frow) * 64; \
    aF[mi][0] = *(const bf16x8*)&As[buf][rA + xs0]; \
    aF[mi][1] = *(const bf16x8*)&As[buf][rA + xs1]; } } while (0)

#define LDB(buf, nh) do { _Pragma("unroll") for (int ni = 0; ni < 2; ++ni) { \
    const int rB = (wn * 64 + (nh) * 32 + ni * 16 + frow) * 64; \
    bF[(nh) * 2 + ni][0] = *(const bf16x8*)&Bs[buf][rB + xs0]; \
    bF[(nh) * 2 + ni][1] = *(const bf16x8*)&Bs[buf][rB + xs1]; } } while (0)

#define MFQ(mh, nh) do { _Pragma("unroll") for (int mi = 0; mi < 4; ++mi) \
  _Pragma("unroll") for (int ni = 0; ni < 2; ++ni) \
  _Pragma("unroll") for (int s = 0; s < 2; ++s) \
    acc[(mh) * 4 + mi][(nh) * 2 + ni] = mf<true>( \
        aF[mi][s], bF[(nh) * 2 + ni][s], acc[(mh) * 4 + mi][(nh) * 2 + ni]); } while (0)

#define TILE4(buf, S2, S3, S4, W1, W2, WV) \
  LDA(buf, 0); LDB(buf, 0); BAR; WAITLGK; PRIO1; MFQ(0, 0); PRIO0; W1; BAR; \
  LDB(buf, 1); S2; BAR; WAITLGK; PRIO1; MFQ(0, 1); PRIO0; W2; BAR; \
  LDA(buf, 1); S3; BAR; WAITLGK; PRIO1; MFQ(1, 1); PRIO0; BAR; \
  S4; BAR; WAITLGK; PRIO1; MFQ(1, 0); PRIO0; WV; BAR;

// out = A @ Bt^T, per-batch Bt (batch = mBase>>12), swapped MFMA, float4 stores.
__global__ __launch_bounds__(512, 2) void gemm8p(
    const u16* __restrict__ A, int lda,
    const u16* __restrict__ Bt, int ldb,
    float* __restrict__ Cq, int ldc, int K, int nTN,
    size_t btStrideB) {
    __shared__ u16 SM[2][2][256 * 64];
    const int tid = threadIdx.x;
    const int wid = tid >> 6, lane = tid & 63;
    const int wm = wid >> 2, wn = wid & 3;

    const int nwg = gridDim.x;
    const int orig = blockIdx.x;
    const int id = (orig & 7) * (nwg >> 3) + (orig >> 3);
    const size_t mBase = (size_t)(id / nTN) * 256;
    const size_t nBase = (size_t)(id % nTN) * 256;

    Bt += (mBase >> 12) * btStrideB;

    const int srow = lane >> 3;
    const int scol = (((lane & 7) ^ (srow & 7)) * 8);

    auto stageH = [&](int buf, int isB, int h, int kt) {
        const u16* g = isB ? Bt : A;
        const int ld = isB ? ldb : lda;
        const size_t rb = isB ? nBase : mBase;
        u16* lds = isB ? Bs[buf] : As[buf];
#pragma unroll
        for (int j = 0; j < 2; ++j) {
            const int rowL = isB ? ((wid >> 1) * 64 + h * 32 + (wid & 1) * 16 + j * 8)
                                 : ((wid >> 2) * 128 + h * 64 + (wid & 3) * 16 + j * 8);
            async16(g + (rb + rowL + srow) * (size_t)ld + (size_t)kt * 64 + scol,
                    lds + rowL * 64);
        }
    };

    const int frow = lane & 15;
    const int xs0 = (((lane >> 4)) ^ (frow & 7)) * 8;
    const int xs1 = ((4 + (lane >> 4)) ^ (frow & 7)) * 8;

    f32x4 acc[8][4] = {};
    bf16x8 aF[4][2], bF[4][2];

#pragma unroll
    for (int h = 0; h < 2; ++h) { stageH(0, 0, h, 0); stageH(0, 1, h, 0); }
#pragma unroll
    for (int h = 0; h < 2; ++h) { stageH(1, 0, h, 1); stageH(1, 1, h, 1); }
    VM(8);
    BAR;

    const int np = K >> 7;
    for (int p = 0; p < np - 1; ++p) {
        const int k2 = 2 * p + 2, k3 = 2 * p + 3;
        TILE4(0,
              { stageH(0, 0, 0, k2); stageH(0, 1, 0, k2); },
              stageH(0, 1, 1, k2),
              stageH(0, 0, 1, k2),
              VM(10), VM(12), VM(12));
        TILE4(1,
              { stageH(1, 0, 0, k3); stageH(1, 1, 0, k3); },
              stageH(1, 1, 1, k3),
              stageH(1, 0, 1, k3),
              VM(10), VM(12), VM(12));
    }
    TILE4(0, , , , , , VM(0));
    TILE4(1, , , , , , );

    const int rb4 = (lane >> 4) * 4;
    const int cx = lane & 15;
#pragma unroll
    for (int m = 0; m < 8; ++m) {
        const size_t row = mBase + wm * 128 + m * 16 + cx;
#pragma unroll
        for (int n = 0; n < 4; ++n) {
            const size_t col = nBase + wn * 64 + n * 16 + rb4;
            *(float4*)&Cq[row * (size_t)ldc + col] = *(float4*)&acc[m][n];
        }
    }
}

// ========== kvw2: fused kv (per b,h) + W2 panels; kv kept in LDS ==========
__global__ __launch_bounds__(256, 2) void kvw2(
    const u16* __restrict__ M1v, const u16* __restrict__ WvT,
    const u16* __restrict__ Wob, u16* __restrict__ W2t) {
    __shared__ u16 Ks[64 * 64];
    __shared__ u16 Vs[64 * 64];
    __shared__ u16 kvs[64 * 64];
    __shared__ u16 Aw[256 * 64];
    const int h = blockIdx.x, b = blockIdx.y;
    const int tid = threadIdx.x, w = tid >> 6, lane = tid & 63;
    const int srow = lane >> 3;
    const int scol = ((lane & 7) ^ srow) * 8;
    const int frow = lane & 15;
    const int xs0 = ((lane >> 4) ^ (frow & 7)) * 8;
    const int xs1 = ((4 + (lane >> 4)) ^ (frow & 7)) * 8;
    const u16* Ap = M1v + (size_t)b * 1048576 + (size_t)h * 64 * 1024;
    const u16* Bp = WvT + (size_t)h * 64 * 1024;
    f32x4 acc[4] = {};
    for (int kk = 0; kk < 16; ++kk) {
        __syncthreads();
#pragma unroll
        for (int j = 0; j < 2; ++j) {
            const int row = w * 16 + j * 8;
            async16(Ap + (size_t)(row + srow) * 1024 + kk * 64 + scol, &Ks[row * 64]);
            async16(Bp + (size_t)(row + srow) * 1024 + kk * 64 + scol, &Vs[row * 64]);
        }
        VM(0);
        __syncthreads();
        bf16x8 a0 = *(const bf16x8*)&Ks[(w * 16 + frow) * 64 + xs0];
        bf16x8 a1 = *(const bf16x8*)&Ks[(w * 16 + frow) * 64 + xs1];
#pragma unroll
        for (int n = 0; n < 4; ++n) {
            bf16x8 b0 = *(const bf16x8*)&Vs[(n * 16 + frow) * 64 + xs0];
            bf16x8 b1 = *(const bf16x8*)&Vs[(n * 16 + frow) * 64 + xs1];
            acc[n] = mf<false>(a0, b0, acc[n]);
            acc[n] = mf<false>(a1, b1, acc[n]);
        }
    }
    {
        const int rb4 = (lane >> 4) * 4, cx = lane & 15;
#pragma unroll
        for (int n = 0; n < 4; ++n) {
            const int col = n * 16 + cx;
            const int unit = col >> 3;
#pragma unroll
            for (int r = 0; r < 4; ++r) {
                const int row = w * 16 + rb4 + r;
                const int byteoff = row * 128 + (((unit ^ (row & 7)) << 4) | ((col & 7) << 1));
                *(u16*)((char*)kvs + byteoff) = f2bf(acc[n][r] * 0.125f);
            }
        }
    }
    __syncthreads();
    u16* outB = W2t + (size_t)b * 1048576;
    for (int eT = 0; eT < 4; ++eT) {
#pragma unroll
        for (int j = 0; j < 8; ++j) {
            const int row = w * 64 + j * 8;
            async16(Wob + (size_t)(eT * 256 + row + srow) * 1024 + h * 64 + scol,
                    &Aw[row * 64]);
        }
        VM(0);
        __syncthreads();
        f32x4 a2[4][4] = {};
#pragma unroll
        for (int m = 0; m < 4; ++m) {
            bf16x8 a0 = *(const bf16x8*)&Aw[(w * 64 + m * 16 + frow) * 64 + xs0];
            bf16x8 a1 = *(const bf16x8*)&Aw[(w * 64 + m * 16 + frow) * 64 + xs1];
#pragma unroll
            for (int n = 0; n < 4; ++n) {
                bf16x8 b0 = *(const bf16x8*)&kvs[(n * 16 + frow) * 64 + xs0];
                bf16x8 b1 = *(const bf16x8*)&kvs[(n * 16 + frow) * 64 + xs1];
                a2[m][n] = mf<false>(a0, b0, a2[m][n]);
                a2[m][n] = mf<false>(a1, b1, a2[m][n]);
            }
        }
        const int rb4 = (lane >> 4) * 4, cx = lane & 15;
#pragma unroll
        for (int m = 0; m < 4; ++m)
#pragma unroll
            for (int n = 0; n < 4; ++n)
#pragma unroll
                for (int r = 0; r < 4; ++r)
                    outB[(size_t)(eT * 256 + w * 64 + m * 16 + rb4 + r) * 1024 +
                         h * 64 + n * 16 + cx] = f2bf(a2[m][n][r]);
        __syncthreads();
    }
}

extern "C" void kernel_launch(void* const* d_in, const int* in_sizes, int n_in,
                              void* d_out, int out_size, void* d_ws, size_t ws_size,
                              hipStream_t stream) {
    const float* x  = (const float*)d_in[0];
    const float* Wq = (const float*)d_in[1];
    const float* Wk = (const float*)d_in[2];
    const float* Wv = (const float*)d_in[3];
    const float* Wo = (const float*)d_in[4];
    float* out = (float*)d_out;
    char* ws = (char*)d_ws;

    u16* xb   = (u16*)(ws);                  // [16384][1024]        32 MB
    u16* xbT  = (u16*)(ws + 33554432);       // [4][1024][4096]      32 MB
    u16* G    = (u16*)(ws + 67108864);       // [4][1024][1024]       8 MB
    u16* M1v  = (u16*)(ws + 75497472);       // [4][1024][1024]       8 MB
    u16* WkvT = (u16*)(ws + 83886080);       // [2048][1024]          4 MB
    u16* Wqb  = (u16*)(ws + 88080384);       // [1024][1024]          2 MB
    u16* Wob  = (u16*)(ws + 90177536);       // [1024][1024]          2 MB
    u16* W2t  = (u16*)(ws + 92798976);       // [4][1024][1024]       8 MB
    u16* W3T  = (u16*)(ws + 101187584);      // [4][1024][1024]       8 MB
    u16* WkT  = WkvT;
    u16* WvT  = WkvT + 1048576;

    prep<<<19456, 256, 0, stream>>>(x, xb, xbT, Wq, Wqb, Wo, Wob, Wk, Wv, WkvT);

    // G_b = x_b^T x_b (bitwise symmetric)
    gemmS<<<256, 512, 0, stream>>>(xbT, 4096, xbT, 4096, G, 1024, 4096, 8,
                                   ~0ULL, 4194304ULL);
    // M1_b = Wk^T G_b (G symmetric -> G rows serve as Bt)
    gemmS<<<256, 512, 0, stream>>>(WkT, 1024, G, 1024, M1v, 1024, 1024, 8,
                                   1023ULL, 1048576ULL);
    // fused kv + W2 panels (kv stays in LDS)
    kvw2<<<dim3(16, 4), 256, 0, stream>>>(M1v, WvT, Wob, W2t);
    // W3T[b*1024+e][d] = sum_k W2t[b][e][k] * Wq[d][k]
    gemmS<<<256, 512, 0, stream>>>(W2t, 1024, Wqb, 1024, W3T, 1024, 1024, 8,
                                   ~0ULL, 0ULL);
    // out = xb @ W3T^T (per-batch Bt); grid 256 (%8==0)
    gemm8p<<<256, 512, 0, stream>>>(xb, 1024, W3T, 1024, out, 1024, 1024, 4, 1048576ULL);
}